// Round 1
// baseline (138.675 us; speedup 1.0000x reference)
//
#include <hip/hip_runtime.h>
#include <cstdint>

#define S_CNT 10000
#define R_CNT 10000

// 16 lanes cooperate on one sample: each lane loads float4 slices of the
// gathered embedding rows (16 lanes x 16B = one full 256B row per load),
// dot-accumulates, then a 16-lane shfl_xor tree reduces; lane 0 applies
// sigmoid and writes the scalar output.
__global__ __launch_bounds__(256) void srct_kernel(
    const int* __restrict__ X,
    const float* __restrict__ s_embeds,
    const float* __restrict__ r_embeds,
    const float* __restrict__ p_embeds,
    float* __restrict__ out, int n)
{
    const int g = threadIdx.x >> 4;    // group index within block (0..15)
    const int l = threadIdx.x & 15;    // lane within group
    const int i = blockIdx.x * 16 + g; // sample index
    if (i >= n) return;

    // All 16 lanes of a group load the same 16B X row (cache broadcast).
    const int4 xi = *reinterpret_cast<const int4*>(X + 4ll * i);
    const int s = xi.x, r = xi.y, p = xi.z, t = xi.w;

    const long long st = (long long)s + (long long)t * S_CNT;
    const long long rt = (long long)r + (long long)t * R_CNT;

    const float4 se = *reinterpret_cast<const float4*>(s_embeds + st * 64 + l * 4);
    const float4 pl = *reinterpret_cast<const float4*>(p_embeds + (long long)p * 128 + l * 4);
    const float4 re = *reinterpret_cast<const float4*>(r_embeds + rt * 64 + l * 4);
    const float4 ph = *reinterpret_cast<const float4*>(p_embeds + (long long)p * 128 + 64 + l * 4);

    float acc = se.x * pl.x + se.y * pl.y + se.z * pl.z + se.w * pl.w
              + re.x * ph.x + re.y * ph.y + re.z * ph.z + re.w * ph.w;

    // Reduce across the 16-lane group (xor masks 1,2,4,8 stay within group).
    acc += __shfl_xor(acc, 1, 64);
    acc += __shfl_xor(acc, 2, 64);
    acc += __shfl_xor(acc, 4, 64);
    acc += __shfl_xor(acc, 8, 64);

    if (l == 0) {
        out[i] = 1.0f / (1.0f + __expf(-acc));
    }
}

extern "C" void kernel_launch(void* const* d_in, const int* in_sizes, int n_in,
                              void* d_out, int out_size, void* d_ws, size_t ws_size,
                              hipStream_t stream) {
    const int*   X        = (const int*)d_in[0];
    const float* s_embeds = (const float*)d_in[1];
    const float* r_embeds = (const float*)d_in[2];
    const float* p_embeds = (const float*)d_in[3];
    float* out = (float*)d_out;

    const int n = in_sizes[0] / 4;          // N samples (X is N x 4)
    const int blocks = (n + 15) / 16;       // 16 samples per 256-thread block
    srct_kernel<<<blocks, 256, 0, stream>>>(X, s_embeds, r_embeds, p_embeds, out, n);
}